// Round 16
// baseline (183.537 us; speedup 1.0000x reference)
//
#include <hip/hip_runtime.h>
#include <hip/hip_bf16.h>
#include <stdint.h>

using bf16 = __hip_bfloat16;
typedef __bf16 bf16x8 __attribute__((ext_vector_type(8)));
typedef float f32x4  __attribute__((ext_vector_type(4)));
typedef float f32x16 __attribute__((ext_vector_type(16)));

#define NB 2
#define NF 16
#define NSP 784
#define SEQ 12544
#define MROWS 25088
#define QSCALE 0.18033688011112042f   // 0.125 * log2(e)

__device__ inline void gload16(const void* g, void* l) {
    __builtin_amdgcn_global_load_lds(
        (const __attribute__((address_space(1))) unsigned int*)g,
        (__attribute__((address_space(3))) unsigned int*)l, 16, 0, 0);
}
__device__ inline ushort f2bu(float x) {
    union { bf16 b; ushort u; } c; c.b = __float2bfloat16(x); return c.u;
}

// ---------------------------------------------------------------------------
// weight convert: [0,196608) = Wqkv (Q rows scaled by QSCALE), rest = Wproj
// ---------------------------------------------------------------------------
__global__ __launch_bounds__(256)
void cvt_w_kernel(const float* __restrict__ wqkv, const float* __restrict__ wproj,
                  ushort* __restrict__ wqkvb, ushort* __restrict__ wpb) {
    int i = blockIdx.x * 256 + threadIdx.x;     // 0..262143
    float4 v;
    ushort4 u;
    if (i < 196608) {
        float s = (i < 65536) ? QSCALE : 1.0f;
        v = ((const float4*)wqkv)[i];
        u.x = f2bu(v.x * s); u.y = f2bu(v.y * s);
        u.z = f2bu(v.z * s); u.w = f2bu(v.w * s);
        ((ushort4*)wqkvb)[i] = u;
    } else {
        int j = i - 196608;
        v = ((const float4*)wproj)[j];
        u.x = f2bu(v.x); u.y = f2bu(v.y); u.z = f2bu(v.z); u.w = f2bu(v.w);
        ((ushort4*)wpb)[j] = u;
    }
}

// ---------------------------------------------------------------------------
// bf16 MFMA GEMM, NT: C[M,N] = A[M,K] * W[N,K]^T, both row-major, BK=64.
// 128x128 tile, 4 waves (2x2), 16x16x32 MFMA. W staged via global_load_lds
// with pre-swizzled source; A staged either the same way (EPI 1, bf16 input)
// or REG-STAGED from fp32 with in-register bf16 convert + swizzled ds_write
// (EPI 0 — fuses the x fp32->bf16 conversion into the GEMM).
// EPI 0 epilogue: Q/K panels (n0<1024) -> coalesced bf16 rows of qkv buffer;
// V panels (n0>=1024) -> TRANSPOSED write directly into vt[pr][64][784]
// (fuses the former vtrans kernel). EPI 1: fp32 out + bias.
// 1D grid with supertile order (4 m-panels x NP n-panels per group).
// ---------------------------------------------------------------------------
template<int EPI>
__global__ __launch_bounds__(256)
void gemm_mfma(const float* __restrict__ Af, const ushort* __restrict__ Ab16,
               const ushort* __restrict__ W, const float* __restrict__ bias,
               ushort* __restrict__ outb, ushort* __restrict__ vtout,
               float* __restrict__ outf, int K, int ldc, int npan)
{
    constexpr int SWZ = 7;
    __shared__ ushort smem[16384];          // 32 KB (A 16K + W 16K)

    const int tid = threadIdx.x;
    const int bid = blockIdx.x;
    const int gsz = 4 * npan;
    const int r   = bid % gsz;
    const int m0 = ((bid / gsz) * 4 + (r & 3)) * 128;
    const int n0 = (r >> 2) * 128;
    const int l  = tid & 63;
    const int wv = tid >> 6;
    const int wm = wv >> 1, wn = wv & 1;
    const int lm = l & 15;
    const int koffb = (l >> 4) * 16;
    const int swz = (lm & SWZ) << 4;

    const int rsub = tid >> 3;              // 8 threads per 128B row-slice
    const int cb0  = (tid & 7) * 16;        // byte granule within row
    const int wofs = (tid >> 6) * 512;

    const size_t ldb = (size_t)K * 2;
    const char* Wb = (const char*)W + (size_t)n0 * ldb;
    const char* Ab = (EPI == 1) ? (const char*)Ab16 + (size_t)m0 * ldb : nullptr;
    const float* Afp = (EPI == 0) ? Af + (size_t)m0 * K : nullptr;

    float4 ar0[4], ar1[4];
    if (EPI == 0) {
#pragma unroll
        for (int i = 0; i < 4; ++i) {
            int row = i * 32 + rsub;
            const float* src = Afp + (size_t)row * K + (tid & 7) * 8;
            ar0[i] = *(const float4*)src;
            ar1[i] = *(const float4*)(src + 4);
        }
    }

    f32x4 acc[4][4] = {};

    for (int k0 = 0; k0 < K; k0 += 64) {
        if (k0) __syncthreads();
#pragma unroll
        for (int i = 0; i < 4; ++i) {
            int row = i * 32 + rsub;
            int cbs = cb0 ^ ((row & SWZ) << 4);
            size_t roff = (size_t)row * ldb + (size_t)(k0 * 2 + cbs);
            gload16(Wb + roff, smem + 8192 + i * 2048 + wofs);
            if (EPI == 1) gload16(Ab + roff, smem + i * 2048 + wofs);
        }
        if (EPI == 0) {     // convert regs -> bf16, write to swizzled LDS col
#pragma unroll
            for (int i = 0; i < 4; ++i) {
                int row = i * 32 + rsub;
                union { ushort us[8]; bf16x8 v; } pk;
                pk.us[0] = f2bu(ar0[i].x); pk.us[1] = f2bu(ar0[i].y);
                pk.us[2] = f2bu(ar0[i].z); pk.us[3] = f2bu(ar0[i].w);
                pk.us[4] = f2bu(ar1[i].x); pk.us[5] = f2bu(ar1[i].y);
                pk.us[6] = f2bu(ar1[i].z); pk.us[7] = f2bu(ar1[i].w);
                int off = row * 64 + ((cb0 ^ ((row & SWZ) << 4)) >> 1);
                *(bf16x8*)&smem[off] = pk.v;
            }
        }
        __syncthreads();
        if (EPI == 0 && k0 + 64 < K) {      // prefetch next BK under MFMA
#pragma unroll
            for (int i = 0; i < 4; ++i) {
                int row = i * 32 + rsub;
                const float* src = Afp + (size_t)row * K + (k0 + 64) + (tid & 7) * 8;
                ar0[i] = *(const float4*)src;
                ar1[i] = *(const float4*)(src + 4);
            }
        }

#pragma unroll
        for (int ks = 0; ks < 2; ++ks) {
            bf16x8 af[4], wf[4];
            const int cb = ((ks * 64 + koffb) ^ swz) >> 1;
#pragma unroll
            for (int f = 0; f < 4; ++f) {
                int rA = wm * 64 + f * 16 + lm;
                int rW = wn * 64 + f * 16 + lm;
                af[f] = *(const bf16x8*)&smem[rA * 64 + cb];
                wf[f] = *(const bf16x8*)&smem[8192 + rW * 64 + cb];
            }
            __builtin_amdgcn_s_setprio(1);
#pragma unroll
            for (int fm = 0; fm < 4; ++fm)
#pragma unroll
                for (int fn = 0; fn < 4; ++fn)
                    acc[fm][fn] = __builtin_amdgcn_mfma_f32_16x16x32_bf16(
                        wf[fn], af[fm], acc[fm][fn], 0, 0, 0);
            __builtin_amdgcn_s_setprio(0);
        }
    }

    // epilogue: lane holds C[m = wm*64+fm*16+lm][n = wn*64+fn*16+(l>>4)*4 + e]
    const int ln4 = (l >> 4) * 4;
    if (EPI == 0) {
        if (n0 < 1024) {       // Q, K panels: coalesced rows of qkv buffer
#pragma unroll
            for (int fm = 0; fm < 4; ++fm) {
                int m = m0 + wm * 64 + fm * 16 + lm;
                ushort* rowp = outb + (size_t)m * ldc + n0 + wn * 64 + ln4;
#pragma unroll
                for (int fn = 0; fn < 4; ++fn) {
                    ushort4 u;
                    u.x = f2bu(acc[fm][fn][0]); u.y = f2bu(acc[fm][fn][1]);
                    u.z = f2bu(acc[fm][fn][2]); u.w = f2bu(acc[fm][fn][3]);
                    *(ushort4*)(rowp + fn * 16) = u;
                }
            }
        } else {               // V panels: transposed scatter into vt[pr][64][784]
            const int hh = ((n0 - 1024) >> 6) + wn;        // wave-uniform head
#pragma unroll
            for (int fm = 0; fm < 4; ++fm) {
                int m = m0 + wm * 64 + fm * 16 + lm;
                int bfi = m / 784;
                int j   = m - bfi * 784;
                ushort* vdst = vtout + ((size_t)(bfi * 8 + hh)) * 50176 + j;
#pragma unroll
                for (int fn = 0; fn < 4; ++fn) {
                    const int dbase = fn * 16 + ln4;
#pragma unroll
                    for (int e = 0; e < 4; ++e)
                        vdst[(size_t)(dbase + e) * 784] = f2bu(acc[fm][fn][e]);
                }
            }
        }
    } else {
#pragma unroll
        for (int fm = 0; fm < 4; ++fm) {
            int m = m0 + wm * 64 + fm * 16 + lm;
            float* rowp = outf + (size_t)m * ldc + n0 + wn * 64 + ln4;
#pragma unroll
            for (int fn = 0; fn < 4; ++fn) {
                float4 b4 = *(const float4*)&bias[n0 + wn * 64 + fn * 16 + ln4];
                float4 o;
                o.x = acc[fm][fn][0] + b4.x; o.y = acc[fm][fn][1] + b4.y;
                o.z = acc[fm][fn][2] + b4.z; o.w = acc[fm][fn][3] + b4.w;
                *(float4*)(rowp + fn * 16) = o;
            }
        }
    }
}

// ---------------------------------------------------------------------------
// MFMA flash attention (32x32x16 bf16), swapped operands. r8 block shape
// (256 thr / 4 waves / 2-buffer depth-1 staging / one barrier per tile)
// + SPLIT ACCUMULATION CHAINS for ILP (the measured limiter is MFMA
// accumulate-latency chains at ~2.75 waves/SIMD):
//  - QK^T: 4 independent depth-2 chains (s0a/s0b/s1a/s1b), summed into
//    the exp2 argument.
//  - PV: 4 persistent accumulators (o0a/o0b/o1a/o1b; js 0,2->a, 1,3->b),
//    summed once in the epilogue — zero per-tile cost.
// launch_bounds(256,3): VGPR cap 170, no spill (r13 lesson).
// P in-register (cvt_pk + permlane32_swap); NO-MAX softmax; XCD-chunked.
// ---------------------------------------------------------------------------
__global__ __launch_bounds__(256, 3)
void attn_mfma(const ushort* __restrict__ qkv, const ushort* __restrict__ vt,
               ushort* __restrict__ oh)
{
    __shared__ __align__(16) ushort Ks[2][4096];   // [j 0..63][d 0..63] swizzled
    __shared__ __align__(16) ushort Vs[2][4096];   // [d 0..63][j 0..63] swizzled
    const int tid = threadIdx.x;
    const int l   = tid & 63;
    const int li  = l & 31;
    const int h5  = l >> 5;
    const int w   = tid >> 6;

    const int bid  = blockIdx.x;
    const int xcd  = bid & 7;
    const int slot = bid >> 3;            // 0..223
    const int pr   = (xcd << 5) + slot / 7;
    const int qt   = slot % 7;
    const int hh   = pr & 7;
    const int bfi  = pr >> 3;
    const size_t rowbase = (size_t)bfi * NSP;
    const int iq = qt * 128 + w * 32 + li;
    const bool qvalid = iq < NSP;
    const int iqc = qvalid ? iq : NSP - 1;

    // Q fragments (held all pass): d = ks*16 + h5*8 + 0..7
    bf16x8 qf[4];
    {
        const ushort* qrow = qkv + (rowbase + iqc) * 1536 + hh * 64 + h5 * 8;
#pragma unroll
        for (int ks = 0; ks < 4; ++ks)
            qf[ks] = *(const bf16x8*)(qrow + ks * 16);
    }

    const char* kb0   = (const char*)(qkv + rowbase * 1536 + 512 + hh * 64);
    const char* vbase = (const char*)(vt + (size_t)pr * (64 * NSP));

    const int srow = tid >> 3;
    const int sg16 = (tid & 7) * 16;

    float l_run = 0.f;
    f32x16 o0a = {}, o0b = {}, o1a = {}, o1b = {};

    const int rsw  = (li & 7) << 4;
    const int base0 = li * 128;
    const int base1 = (32 + li) * 128;

    // ---- prologue: stage tile 0 into buf 0 ----
#pragma unroll
    for (int i = 0; i < 2; ++i) {
        int row = i * 32 + srow;
        int swz = sg16 ^ ((row & 7) << 4);
        gload16(kb0 + (size_t)row * 3072 + swz, &Ks[0][i * 2048 + tid * 8]);
        gload16(vbase + (size_t)row * 1568 + swz, &Vs[0][i * 2048 + tid * 8]);
    }
    __syncthreads();

    int cur = 0;
    for (int t = 0; t < 13; ++t) {
        const int j0 = t * 64;
        // ---- issue next-tile stage into other buffer ----
        if (t < 12) {
            const int jn = j0 + 64;
#pragma unroll
            for (int i = 0; i < 2; ++i) {
                int row = i * 32 + srow;
                int swz = sg16 ^ ((row & 7) << 4);
                int jr = jn + row; if (jr > NSP - 1) jr = NSP - 1;
                gload16(kb0 + (size_t)jr * 3072 + swz, &Ks[cur ^ 1][i * 2048 + tid * 8]);
                int cb = jn * 2 + swz;
                if (cb + 16 > NSP * 2) cb = jn * 2;   // tail: stay in valid row data
                gload16(vbase + (size_t)row * 1568 + cb, &Vs[cur ^ 1][i * 2048 + tid * 8]);
            }
        }

        const char* KsC = (const char*)&Ks[cur][0];
        const char* VsC = (const char*)&Vs[cur][0];

        // ---- S^T = mfma(K, Q): 4 independent depth-2 chains ----
        f32x16 s0a = {}, s0b = {}, s1a = {}, s1b = {};
        __builtin_amdgcn_s_setprio(1);
#pragma unroll
        for (int ks = 0; ks < 4; ++ks) {
            int cb = (ks * 32 + h5 * 16) ^ rsw;
            bf16x8 k0 = *(const bf16x8*)(KsC + base0 + cb);
            bf16x8 k1 = *(const bf16x8*)(KsC + base1 + cb);
            if (ks & 1) {
                s0b = __builtin_amdgcn_mfma_f32_32x32x16_bf16(k0, qf[ks], s0b, 0, 0, 0);
                s1b = __builtin_amdgcn_mfma_f32_32x32x16_bf16(k1, qf[ks], s1b, 0, 0, 0);
            } else {
                s0a = __builtin_amdgcn_mfma_f32_32x32x16_bf16(k0, qf[ks], s0a, 0, 0, 0);
                s1a = __builtin_amdgcn_mfma_f32_32x32x16_bf16(k1, qf[ks], s1a, 0, 0, 0);
            }
        }
        __builtin_amdgcn_s_setprio(0);

        // ---- no-max softmax: p = exp2(s_a + s_b), l += sum(p) ----
        float p0[16], p1[16];
        float rs = 0.f;
        if (j0 + 64 > NSP) {
#pragma unroll
            for (int r = 0; r < 16; ++r) {
                int jl = (r & 3) + 8 * (r >> 2) + 4 * h5;
                float v0 = s0a[r] + s0b[r];
                float v1 = s1a[r] + s1b[r];
                if (j0 + jl >= NSP)      v0 = -1e30f;   // exp2 -> exact 0
                if (j0 + 32 + jl >= NSP) v1 = -1e30f;
                p0[r] = exp2f(v0); rs += p0[r];
                p1[r] = exp2f(v1); rs += p1[r];
            }
        } else {
#pragma unroll
            for (int r = 0; r < 16; ++r) {
                p0[r] = exp2f(s0a[r] + s0b[r]); rs += p0[r];
                p1[r] = exp2f(s1a[r] + s1b[r]); rs += p1[r];
            }
        }
        rs += __shfl_xor(rs, 32);
        l_run += rs;

        // ---- PV: P via cvt_pk + permlane32_swap; split o-chains (a/b) ----
#pragma unroll
        for (int js = 0; js < 4; ++js) {
            const int rb = (js & 1) * 8;
            float e0 = (js < 2) ? p0[rb + 0] : p1[rb + 0];
            float e1 = (js < 2) ? p0[rb + 1] : p1[rb + 1];
            float e2 = (js < 2) ? p0[rb + 2] : p1[rb + 2];
            float e3 = (js < 2) ? p0[rb + 3] : p1[rb + 3];
            float e4 = (js < 2) ? p0[rb + 4] : p1[rb + 4];
            float e5 = (js < 2) ? p0[rb + 5] : p1[rb + 5];
            float e6 = (js < 2) ? p0[rb + 6] : p1[rb + 6];
            float e7 = (js < 2) ? p0[rb + 7] : p1[rb + 7];
            uint A0, A1, B0, B1;
            asm("v_cvt_pk_bf16_f32 %0, %1, %2" : "=v"(A0) : "v"(e0), "v"(e1));
            asm("v_cvt_pk_bf16_f32 %0, %1, %2" : "=v"(A1) : "v"(e2), "v"(e3));
            asm("v_cvt_pk_bf16_f32 %0, %1, %2" : "=v"(B0) : "v"(e4), "v"(e5));
            asm("v_cvt_pk_bf16_f32 %0, %1, %2" : "=v"(B1) : "v"(e6), "v"(e7));
            asm volatile("v_permlane32_swap_b32 %0, %1" : "+v"(A0), "+v"(B0));
            asm volatile("v_permlane32_swap_b32 %0, %1" : "+v"(A1), "+v"(B1));
            union { uint u[4]; bf16x8 v; } pf;
            pf.u[0] = A0; pf.u[1] = A1; pf.u[2] = B0; pf.u[3] = B1;

            int cb = (js * 32 + h5 * 16) ^ rsw;
            bf16x8 v0f = *(const bf16x8*)(VsC + base0 + cb);
            bf16x8 v1f = *(const bf16x8*)(VsC + base1 + cb);
            __builtin_amdgcn_s_setprio(1);
            if (js & 1) {
                o0b = __builtin_amdgcn_mfma_f32_32x32x16_bf16(v0f, pf.v, o0b, 0, 0, 0);
                o1b = __builtin_amdgcn_mfma_f32_32x32x16_bf16(v1f, pf.v, o1b, 0, 0, 0);
            } else {
                o0a = __builtin_amdgcn_mfma_f32_32x32x16_bf16(v0f, pf.v, o0a, 0, 0, 0);
                o1a = __builtin_amdgcn_mfma_f32_32x32x16_bf16(v1f, pf.v, o1a, 0, 0, 0);
            }
            __builtin_amdgcn_s_setprio(0);
        }

        __syncthreads();   // drains vmcnt (next-tile stage) + buffer swap
        cur ^= 1;
    }

    if (qvalid) {
        float inv = 1.0f / l_run;
        size_t ro = (rowbase + iq) * 512 + hh * 64;
#pragma unroll
        for (int g = 0; g < 4; ++g) {
            int d = g * 8 + h5 * 4;
            ushort4 uh0, uh1;
#pragma unroll
            for (int m = 0; m < 4; ++m) {
                ((ushort*)&uh0)[m] = f2bu((o0a[g * 4 + m] + o0b[g * 4 + m]) * inv);
                ((ushort*)&uh1)[m] = f2bu((o1a[g * 4 + m] + o1b[g * 4 + m]) * inv);
            }
            *(ushort4*)&oh[ro + d]      = uh0;
            *(ushort4*)&oh[ro + 32 + d] = uh1;
        }
    }
}

// ---------------------------------------------------------------------------
extern "C" void kernel_launch(void* const* d_in, const int* in_sizes, int n_in,
                              void* d_out, int out_size, void* d_ws, size_t ws_size,
                              hipStream_t stream) {
    const float* x     = (const float*)d_in[0];   // [2,12544,512]
    const float* Wqkv  = (const float*)d_in[1];   // [1536,512]
    const float* Wproj = (const float*)d_in[2];   // [512,512]
    const float* bproj = (const float*)d_in[3];   // [512]
    float* out = (float*)d_out;

    char* ws = (char*)d_ws;
    ushort* aout  = (ushort*)(ws);                 // 25,690,112 B: attn-out bf16
    ushort* qkvb  = (ushort*)(ws + 25690112);      // 77,070,336 B: q|k|(v unused) bf16
    ushort* wqkvb = (ushort*)(ws + 102760448);     //  1,572,864 B
    ushort* wpb   = (ushort*)(ws + 104333312);     //    524,288 B

    // Vt lives in d_out (51.4 MB fp32 buffer; we need 25.7 MB bf16), written
    // directly by the QKV GEMM's V-panel epilogue (transposed), consumed by
    // attn_mfma, then overwritten by the proj GEMM's final output.
    ushort* vtb = (ushort*)d_out;

    dim3 blk(256);
    cvt_w_kernel<<<1024, blk, 0, stream>>>(Wqkv, Wproj, wqkvb, wpb);

    // QKV: fp32 x (fused bf16 cvt) x Wqkv^T -> Q,K rows in qkvb + Vt in d_out
    gemm_mfma<0><<<dim3(2352), blk, 0, stream>>>(
        x, nullptr, wqkvb, nullptr, qkvb, vtb, nullptr, 512, 1536, 12);

    // spatial attention -> bf16 [25088,512]
    attn_mfma<<<dim3(1792), blk, 0, stream>>>(qkvb, vtb, aout);

    // proj: plain bf16 GEMM + bias -> fp32 out
    gemm_mfma<1><<<dim3(784), blk, 0, stream>>>(
        nullptr, aout, wpb, bproj, nullptr, nullptr, out, 512, 512, 4);
}

// Round 17
// 179.773 us; speedup vs baseline: 1.0209x; 1.0209x over previous
//
#include <hip/hip_runtime.h>
#include <hip/hip_bf16.h>
#include <stdint.h>

using bf16 = __hip_bfloat16;
typedef __bf16 bf16x8 __attribute__((ext_vector_type(8)));
typedef float f32x4  __attribute__((ext_vector_type(4)));
typedef float f32x16 __attribute__((ext_vector_type(16)));

#define NB 2
#define NF 16
#define NSP 784
#define SEQ 12544
#define MROWS 25088
#define QSCALE 0.18033688011112042f   // 0.125 * log2(e)

__device__ inline void gload16(const void* g, void* l) {
    __builtin_amdgcn_global_load_lds(
        (const __attribute__((address_space(1))) unsigned int*)g,
        (__attribute__((address_space(3))) unsigned int*)l, 16, 0, 0);
}
__device__ inline ushort f2bu(float x) {
    union { bf16 b; ushort u; } c; c.b = __float2bfloat16(x); return c.u;
}

// ---------------------------------------------------------------------------
// weight convert: [0,196608) = Wqkv (Q rows scaled by QSCALE), rest = Wproj
// ---------------------------------------------------------------------------
__global__ __launch_bounds__(256)
void cvt_w_kernel(const float* __restrict__ wqkv, const float* __restrict__ wproj,
                  ushort* __restrict__ wqkvb, ushort* __restrict__ wpb) {
    int i = blockIdx.x * 256 + threadIdx.x;     // 0..262143
    float4 v;
    ushort4 u;
    if (i < 196608) {
        float s = (i < 65536) ? QSCALE : 1.0f;
        v = ((const float4*)wqkv)[i];
        u.x = f2bu(v.x * s); u.y = f2bu(v.y * s);
        u.z = f2bu(v.z * s); u.w = f2bu(v.w * s);
        ((ushort4*)wqkvb)[i] = u;
    } else {
        int j = i - 196608;
        v = ((const float4*)wproj)[j];
        u.x = f2bu(v.x); u.y = f2bu(v.y); u.z = f2bu(v.z); u.w = f2bu(v.w);
        ((ushort4*)wpb)[j] = u;
    }
}

// ---------------------------------------------------------------------------
// bf16 MFMA GEMM, NT: C[M,N] = A[M,K] * W[N,K]^T, both row-major, BK=64.
// 128x128 tile, 4 waves (2x2), 16x16x32 MFMA. W staged via global_load_lds
// with pre-swizzled source; A staged either the same way (EPI 1, bf16 input)
// or REG-STAGED from fp32 with in-register bf16 convert + swizzled ds_write
// (EPI 0 — fuses the x fp32->bf16 conversion into the GEMM).
// EPI 0 epilogue: Q/K panels (n0<1024) -> coalesced bf16 rows of qkv buffer;
// V panels (n0>=1024) -> TRANSPOSED write directly into vt[pr][64][784]
// (fuses the former vtrans kernel). EPI 1: fp32 out + bias.
// 1D grid with supertile order (4 m-panels x NP n-panels per group).
// ---------------------------------------------------------------------------
template<int EPI>
__global__ __launch_bounds__(256)
void gemm_mfma(const float* __restrict__ Af, const ushort* __restrict__ Ab16,
               const ushort* __restrict__ W, const float* __restrict__ bias,
               ushort* __restrict__ outb, ushort* __restrict__ vtout,
               float* __restrict__ outf, int K, int ldc, int npan)
{
    constexpr int SWZ = 7;
    __shared__ ushort smem[16384];          // 32 KB (A 16K + W 16K)

    const int tid = threadIdx.x;
    const int bid = blockIdx.x;
    const int gsz = 4 * npan;
    const int r   = bid % gsz;
    const int m0 = ((bid / gsz) * 4 + (r & 3)) * 128;
    const int n0 = (r >> 2) * 128;
    const int l  = tid & 63;
    const int wv = tid >> 6;
    const int wm = wv >> 1, wn = wv & 1;
    const int lm = l & 15;
    const int koffb = (l >> 4) * 16;
    const int swz = (lm & SWZ) << 4;

    const int rsub = tid >> 3;              // 8 threads per 128B row-slice
    const int cb0  = (tid & 7) * 16;        // byte granule within row
    const int wofs = (tid >> 6) * 512;

    const size_t ldb = (size_t)K * 2;
    const char* Wb = (const char*)W + (size_t)n0 * ldb;
    const char* Ab = (EPI == 1) ? (const char*)Ab16 + (size_t)m0 * ldb : nullptr;
    const float* Afp = (EPI == 0) ? Af + (size_t)m0 * K : nullptr;

    float4 ar0[4], ar1[4];
    if (EPI == 0) {
#pragma unroll
        for (int i = 0; i < 4; ++i) {
            int row = i * 32 + rsub;
            const float* src = Afp + (size_t)row * K + (tid & 7) * 8;
            ar0[i] = *(const float4*)src;
            ar1[i] = *(const float4*)(src + 4);
        }
    }

    f32x4 acc[4][4] = {};

    for (int k0 = 0; k0 < K; k0 += 64) {
        if (k0) __syncthreads();
#pragma unroll
        for (int i = 0; i < 4; ++i) {
            int row = i * 32 + rsub;
            int cbs = cb0 ^ ((row & SWZ) << 4);
            size_t roff = (size_t)row * ldb + (size_t)(k0 * 2 + cbs);
            gload16(Wb + roff, smem + 8192 + i * 2048 + wofs);
            if (EPI == 1) gload16(Ab + roff, smem + i * 2048 + wofs);
        }
        if (EPI == 0) {     // convert regs -> bf16, write to swizzled LDS col
#pragma unroll
            for (int i = 0; i < 4; ++i) {
                int row = i * 32 + rsub;
                union { ushort us[8]; bf16x8 v; } pk;
                pk.us[0] = f2bu(ar0[i].x); pk.us[1] = f2bu(ar0[i].y);
                pk.us[2] = f2bu(ar0[i].z); pk.us[3] = f2bu(ar0[i].w);
                pk.us[4] = f2bu(ar1[i].x); pk.us[5] = f2bu(ar1[i].y);
                pk.us[6] = f2bu(ar1[i].z); pk.us[7] = f2bu(ar1[i].w);
                int off = row * 64 + ((cb0 ^ ((row & SWZ) << 4)) >> 1);
                *(bf16x8*)&smem[off] = pk.v;
            }
        }
        __syncthreads();
        if (EPI == 0 && k0 + 64 < K) {      // prefetch next BK under MFMA
#pragma unroll
            for (int i = 0; i < 4; ++i) {
                int row = i * 32 + rsub;
                const float* src = Afp + (size_t)row * K + (k0 + 64) + (tid & 7) * 8;
                ar0[i] = *(const float4*)src;
                ar1[i] = *(const float4*)(src + 4);
            }
        }

#pragma unroll
        for (int ks = 0; ks < 2; ++ks) {
            bf16x8 af[4], wf[4];
            const int cb = ((ks * 64 + koffb) ^ swz) >> 1;
#pragma unroll
            for (int f = 0; f < 4; ++f) {
                int rA = wm * 64 + f * 16 + lm;
                int rW = wn * 64 + f * 16 + lm;
                af[f] = *(const bf16x8*)&smem[rA * 64 + cb];
                wf[f] = *(const bf16x8*)&smem[8192 + rW * 64 + cb];
            }
            __builtin_amdgcn_s_setprio(1);
#pragma unroll
            for (int fm = 0; fm < 4; ++fm)
#pragma unroll
                for (int fn = 0; fn < 4; ++fn)
                    acc[fm][fn] = __builtin_amdgcn_mfma_f32_16x16x32_bf16(
                        wf[fn], af[fm], acc[fm][fn], 0, 0, 0);
            __builtin_amdgcn_s_setprio(0);
        }
    }

    // epilogue: lane holds C[m = wm*64+fm*16+lm][n = wn*64+fn*16+(l>>4)*4 + e]
    const int ln4 = (l >> 4) * 4;
    if (EPI == 0) {
        if (n0 < 1024) {       // Q, K panels: coalesced rows of qkv buffer
#pragma unroll
            for (int fm = 0; fm < 4; ++fm) {
                int m = m0 + wm * 64 + fm * 16 + lm;
                ushort* rowp = outb + (size_t)m * ldc + n0 + wn * 64 + ln4;
#pragma unroll
                for (int fn = 0; fn < 4; ++fn) {
                    ushort4 u;
                    u.x = f2bu(acc[fm][fn][0]); u.y = f2bu(acc[fm][fn][1]);
                    u.z = f2bu(acc[fm][fn][2]); u.w = f2bu(acc[fm][fn][3]);
                    *(ushort4*)(rowp + fn * 16) = u;
                }
            }
        } else {               // V panels: transposed scatter into vt[pr][64][784]
            const int hh = ((n0 - 1024) >> 6) + wn;        // wave-uniform head
#pragma unroll
            for (int fm = 0; fm < 4; ++fm) {
                int m = m0 + wm * 64 + fm * 16 + lm;
                int bfi = m / 784;
                int j   = m - bfi * 784;
                ushort* vdst = vtout + ((size_t)(bfi * 8 + hh)) * 50176 + j;
#pragma unroll
                for (int fn = 0; fn < 4; ++fn) {
                    const int dbase = fn * 16 + ln4;
#pragma unroll
                    for (int e = 0; e < 4; ++e)
                        vdst[(size_t)(dbase + e) * 784] = f2bu(acc[fm][fn][e]);
                }
            }
        }
    } else {
#pragma unroll
        for (int fm = 0; fm < 4; ++fm) {
            int m = m0 + wm * 64 + fm * 16 + lm;
            float* rowp = outf + (size_t)m * ldc + n0 + wn * 64 + ln4;
#pragma unroll
            for (int fn = 0; fn < 4; ++fn) {
                float4 b4 = *(const float4*)&bias[n0 + wn * 64 + fn * 16 + ln4];
                float4 o;
                o.x = acc[fm][fn][0] + b4.x; o.y = acc[fm][fn][1] + b4.y;
                o.z = acc[fm][fn][2] + b4.z; o.w = acc[fm][fn][3] + b4.w;
                *(float4*)(rowp + fn * 16) = o;
            }
        }
    }
}

// ---------------------------------------------------------------------------
// MFMA flash attention (32x32x16 bf16), swapped operands — the round-8
// configuration verbatim (measured 88-89.6us): 256 thr = 4 waves, 32 q-rows
// per wave, 2-buffer depth-1 staging via global_load_lds + both-sides XOR
// swizzle, one __syncthreads per k-tile, P in-register (cvt_pk +
// permlane32_swap), NO-MAX softmax with VALU sum. XCD-chunked grid.
// Structural experiments (r9 2-wave/64-row, r10 dacc-MFMA, r11 depth-2
// counted-vmcnt, r13 8-wave, r16 split-chains) ALL measured worse — this
// shape is a robust local optimum; do not perturb without within-probe A/B.
// ---------------------------------------------------------------------------
__global__ __launch_bounds__(256, 4)
void attn_mfma(const ushort* __restrict__ qkv, const ushort* __restrict__ vt,
               ushort* __restrict__ oh)
{
    __shared__ __align__(16) ushort Ks[2][4096];   // [j 0..63][d 0..63] swizzled
    __shared__ __align__(16) ushort Vs[2][4096];   // [d 0..63][j 0..63] swizzled
    const int tid = threadIdx.x;
    const int l   = tid & 63;
    const int li  = l & 31;
    const int h5  = l >> 5;
    const int w   = tid >> 6;

    const int bid  = blockIdx.x;
    const int xcd  = bid & 7;
    const int slot = bid >> 3;            // 0..223
    const int pr   = (xcd << 5) + slot / 7;
    const int qt   = slot % 7;
    const int hh   = pr & 7;
    const int bfi  = pr >> 3;
    const size_t rowbase = (size_t)bfi * NSP;
    const int iq = qt * 128 + w * 32 + li;
    const bool qvalid = iq < NSP;
    const int iqc = qvalid ? iq : NSP - 1;

    // Q fragments (held all pass): d = ks*16 + h5*8 + 0..7
    bf16x8 qf[4];
    {
        const ushort* qrow = qkv + (rowbase + iqc) * 1536 + hh * 64 + h5 * 8;
#pragma unroll
        for (int ks = 0; ks < 4; ++ks)
            qf[ks] = *(const bf16x8*)(qrow + ks * 16);
    }

    const char* kb0   = (const char*)(qkv + rowbase * 1536 + 512 + hh * 64);
    const char* vbase = (const char*)(vt + (size_t)pr * (64 * NSP));

    const int srow = tid >> 3;
    const int sg16 = (tid & 7) * 16;

    float l_run = 0.f;
    f32x16 o0 = {}, o1 = {};

    const int rsw  = (li & 7) << 4;
    const int base0 = li * 128;
    const int base1 = (32 + li) * 128;

    // ---- prologue: stage tile 0 into buf 0 ----
#pragma unroll
    for (int i = 0; i < 2; ++i) {
        int row = i * 32 + srow;
        int swz = sg16 ^ ((row & 7) << 4);
        gload16(kb0 + (size_t)row * 3072 + swz, &Ks[0][i * 2048 + tid * 8]);
        gload16(vbase + (size_t)row * 1568 + swz, &Vs[0][i * 2048 + tid * 8]);
    }
    __syncthreads();

    int cur = 0;
    for (int t = 0; t < 13; ++t) {
        const int j0 = t * 64;
        // ---- issue next-tile stage into other buffer ----
        if (t < 12) {
            const int jn = j0 + 64;
#pragma unroll
            for (int i = 0; i < 2; ++i) {
                int row = i * 32 + srow;
                int swz = sg16 ^ ((row & 7) << 4);
                int jr = jn + row; if (jr > NSP - 1) jr = NSP - 1;
                gload16(kb0 + (size_t)jr * 3072 + swz, &Ks[cur ^ 1][i * 2048 + tid * 8]);
                int cb = jn * 2 + swz;
                if (cb + 16 > NSP * 2) cb = jn * 2;   // tail: stay in valid row data
                gload16(vbase + (size_t)row * 1568 + cb, &Vs[cur ^ 1][i * 2048 + tid * 8]);
            }
        }

        const char* KsC = (const char*)&Ks[cur][0];
        const char* VsC = (const char*)&Vs[cur][0];

        // ---- S^T = mfma(K, Q) ----
        f32x16 s0 = {}, s1 = {};
        __builtin_amdgcn_s_setprio(1);
#pragma unroll
        for (int ks = 0; ks < 4; ++ks) {
            int cb = (ks * 32 + h5 * 16) ^ rsw;
            bf16x8 k0 = *(const bf16x8*)(KsC + base0 + cb);
            bf16x8 k1 = *(const bf16x8*)(KsC + base1 + cb);
            s0 = __builtin_amdgcn_mfma_f32_32x32x16_bf16(k0, qf[ks], s0, 0, 0, 0);
            s1 = __builtin_amdgcn_mfma_f32_32x32x16_bf16(k1, qf[ks], s1, 0, 0, 0);
        }
        __builtin_amdgcn_s_setprio(0);

        if (j0 + 64 > NSP) {   // tail mask -> exp2 gives exact 0
#pragma unroll
            for (int r = 0; r < 16; ++r) {
                int jl = (r & 3) + 8 * (r >> 2) + 4 * h5;
                if (j0 + jl >= NSP)      s0[r] = -1e30f;
                if (j0 + 32 + jl >= NSP) s1[r] = -1e30f;
            }
        }

        // ---- no-max softmax: p = exp2(s), l += sum(p) ----
        float p0[16], p1[16];
        float rs = 0.f;
#pragma unroll
        for (int r = 0; r < 16; ++r) { p0[r] = exp2f(s0[r]); rs += p0[r]; }
#pragma unroll
        for (int r = 0; r < 16; ++r) { p1[r] = exp2f(s1[r]); rs += p1[r]; }
        rs += __shfl_xor(rs, 32);
        l_run += rs;

        // ---- PV: P fragment via cvt_pk + permlane32_swap (no LDS) ----
#pragma unroll
        for (int js = 0; js < 4; ++js) {
            const int rb = (js & 1) * 8;
            float e0 = (js < 2) ? p0[rb + 0] : p1[rb + 0];
            float e1 = (js < 2) ? p0[rb + 1] : p1[rb + 1];
            float e2 = (js < 2) ? p0[rb + 2] : p1[rb + 2];
            float e3 = (js < 2) ? p0[rb + 3] : p1[rb + 3];
            float e4 = (js < 2) ? p0[rb + 4] : p1[rb + 4];
            float e5 = (js < 2) ? p0[rb + 5] : p1[rb + 5];
            float e6 = (js < 2) ? p0[rb + 6] : p1[rb + 6];
            float e7 = (js < 2) ? p0[rb + 7] : p1[rb + 7];
            uint A0, A1, B0, B1;
            asm("v_cvt_pk_bf16_f32 %0, %1, %2" : "=v"(A0) : "v"(e0), "v"(e1));
            asm("v_cvt_pk_bf16_f32 %0, %1, %2" : "=v"(A1) : "v"(e2), "v"(e3));
            asm("v_cvt_pk_bf16_f32 %0, %1, %2" : "=v"(B0) : "v"(e4), "v"(e5));
            asm("v_cvt_pk_bf16_f32 %0, %1, %2" : "=v"(B1) : "v"(e6), "v"(e7));
            asm volatile("v_permlane32_swap_b32 %0, %1" : "+v"(A0), "+v"(B0));
            asm volatile("v_permlane32_swap_b32 %0, %1" : "+v"(A1), "+v"(B1));
            union { uint u[4]; bf16x8 v; } pf;
            pf.u[0] = A0; pf.u[1] = A1; pf.u[2] = B0; pf.u[3] = B1;

            int cb = (js * 32 + h5 * 16) ^ rsw;
            bf16x8 v0f = *(const bf16x8*)(VsC + base0 + cb);
            bf16x8 v1f = *(const bf16x8*)(VsC + base1 + cb);
            __builtin_amdgcn_s_setprio(1);
            o0 = __builtin_amdgcn_mfma_f32_32x32x16_bf16(v0f, pf.v, o0, 0, 0, 0);
            o1 = __builtin_amdgcn_mfma_f32_32x32x16_bf16(v1f, pf.v, o1, 0, 0, 0);
            __builtin_amdgcn_s_setprio(0);
        }

        __syncthreads();   // drains vmcnt (next-tile stage) + buffer swap
        cur ^= 1;
    }

    if (qvalid) {
        float inv = 1.0f / l_run;
        size_t ro = (rowbase + iq) * 512 + hh * 64;
#pragma unroll
        for (int g = 0; g < 4; ++g) {
            int d = g * 8 + h5 * 4;
            ushort4 uh0, uh1;
#pragma unroll
            for (int m = 0; m < 4; ++m) {
                ((ushort*)&uh0)[m] = f2bu(o0[g * 4 + m] * inv);
                ((ushort*)&uh1)[m] = f2bu(o1[g * 4 + m] * inv);
            }
            *(ushort4*)&oh[ro + d]      = uh0;
            *(ushort4*)&oh[ro + 32 + d] = uh1;
        }
    }
}

// ---------------------------------------------------------------------------
extern "C" void kernel_launch(void* const* d_in, const int* in_sizes, int n_in,
                              void* d_out, int out_size, void* d_ws, size_t ws_size,
                              hipStream_t stream) {
    const float* x     = (const float*)d_in[0];   // [2,12544,512]
    const float* Wqkv  = (const float*)d_in[1];   // [1536,512]
    const float* Wproj = (const float*)d_in[2];   // [512,512]
    const float* bproj = (const float*)d_in[3];   // [512]
    float* out = (float*)d_out;

    char* ws = (char*)d_ws;
    ushort* aout  = (ushort*)(ws);                 // 25,690,112 B: attn-out bf16
    ushort* qkvb  = (ushort*)(ws + 25690112);      // 77,070,336 B: q|k|(v unused) bf16
    ushort* wqkvb = (ushort*)(ws + 102760448);     //  1,572,864 B
    ushort* wpb   = (ushort*)(ws + 104333312);     //    524,288 B

    // Vt lives in d_out (51.4 MB fp32 buffer; we need 25.7 MB bf16), written
    // directly by the QKV GEMM's V-panel epilogue (transposed), consumed by
    // attn_mfma, then overwritten by the proj GEMM's final output.
    ushort* vtb = (ushort*)d_out;

    dim3 blk(256);
    cvt_w_kernel<<<1024, blk, 0, stream>>>(Wqkv, Wproj, wqkvb, wpb);

    // QKV: fp32 x (fused bf16 cvt) x Wqkv^T -> Q,K rows in qkvb + Vt in d_out
    gemm_mfma<0><<<dim3(2352), blk, 0, stream>>>(
        x, nullptr, wqkvb, nullptr, qkvb, vtb, nullptr, 512, 1536, 12);

    // spatial attention -> bf16 [25088,512]
    attn_mfma<<<dim3(1792), blk, 0, stream>>>(qkvb, vtb, aout);

    // proj: plain bf16 GEMM + bias -> fp32 out
    gemm_mfma<1><<<dim3(784), blk, 0, stream>>>(
        nullptr, aout, wpb, bproj, nullptr, nullptr, out, 512, 512, 4);
}

// Round 18
// 179.504 us; speedup vs baseline: 1.0225x; 1.0015x over previous
//
#include <hip/hip_runtime.h>
#include <hip/hip_bf16.h>
#include <stdint.h>

using bf16 = __hip_bfloat16;
typedef __bf16 bf16x8 __attribute__((ext_vector_type(8)));
typedef float f32x4  __attribute__((ext_vector_type(4)));
typedef float f32x16 __attribute__((ext_vector_type(16)));

#define NB 2
#define NF 16
#define NSP 784
#define SEQ 12544
#define MROWS 25088
#define QSCALE 0.18033688011112042f   // 0.125 * log2(e)

__device__ inline void gload16(const void* g, void* l) {
    __builtin_amdgcn_global_load_lds(
        (const __attribute__((address_space(1))) unsigned int*)g,
        (__attribute__((address_space(3))) unsigned int*)l, 16, 0, 0);
}
__device__ inline ushort f2bu(float x) {
    union { bf16 b; ushort u; } c; c.b = __float2bfloat16(x); return c.u;
}

// ---------------------------------------------------------------------------
// weight convert: [0,196608) = Wqkv (Q rows scaled by QSCALE), rest = Wproj
// ---------------------------------------------------------------------------
__global__ __launch_bounds__(256)
void cvt_w_kernel(const float* __restrict__ wqkv, const float* __restrict__ wproj,
                  ushort* __restrict__ wqkvb, ushort* __restrict__ wpb) {
    int i = blockIdx.x * 256 + threadIdx.x;     // 0..262143
    float4 v;
    ushort4 u;
    if (i < 196608) {
        float s = (i < 65536) ? QSCALE : 1.0f;
        v = ((const float4*)wqkv)[i];
        u.x = f2bu(v.x * s); u.y = f2bu(v.y * s);
        u.z = f2bu(v.z * s); u.w = f2bu(v.w * s);
        ((ushort4*)wqkvb)[i] = u;
    } else {
        int j = i - 196608;
        v = ((const float4*)wproj)[j];
        u.x = f2bu(v.x); u.y = f2bu(v.y); u.z = f2bu(v.z); u.w = f2bu(v.w);
        ((ushort4*)wpb)[j] = u;
    }
}

// ---------------------------------------------------------------------------
// bf16 MFMA GEMM, NT: C[M,N] = A[M,K] * W[N,K]^T, both row-major, BK=64.
// 128x128 tile, 4 waves (2x2), 16x16x32 MFMA. W staged via global_load_lds
// with pre-swizzled source; A staged either the same way (EPI 1, bf16 input)
// or REG-STAGED from fp32 with in-register bf16 convert + swizzled ds_write
// (EPI 0 — fuses the x fp32->bf16 conversion into the GEMM).
// EPI 0 epilogue: Q/K panels (n0<1024) -> coalesced bf16 rows of qkv buffer;
// V panels (n0>=1024) -> TRANSPOSED write directly into vt[pr][64][784]
// (fuses the former vtrans kernel). EPI 1: fp32 out + bias.
// 1D grid with supertile order (4 m-panels x NP n-panels per group).
// ---------------------------------------------------------------------------
template<int EPI>
__global__ __launch_bounds__(256)
void gemm_mfma(const float* __restrict__ Af, const ushort* __restrict__ Ab16,
               const ushort* __restrict__ W, const float* __restrict__ bias,
               ushort* __restrict__ outb, ushort* __restrict__ vtout,
               float* __restrict__ outf, int K, int ldc, int npan)
{
    constexpr int SWZ = 7;
    __shared__ ushort smem[16384];          // 32 KB (A 16K + W 16K)

    const int tid = threadIdx.x;
    const int bid = blockIdx.x;
    const int gsz = 4 * npan;
    const int r   = bid % gsz;
    const int m0 = ((bid / gsz) * 4 + (r & 3)) * 128;
    const int n0 = (r >> 2) * 128;
    const int l  = tid & 63;
    const int wv = tid >> 6;
    const int wm = wv >> 1, wn = wv & 1;
    const int lm = l & 15;
    const int koffb = (l >> 4) * 16;
    const int swz = (lm & SWZ) << 4;

    const int rsub = tid >> 3;              // 8 threads per 128B row-slice
    const int cb0  = (tid & 7) * 16;        // byte granule within row
    const int wofs = (tid >> 6) * 512;

    const size_t ldb = (size_t)K * 2;
    const char* Wb = (const char*)W + (size_t)n0 * ldb;
    const char* Ab = (EPI == 1) ? (const char*)Ab16 + (size_t)m0 * ldb : nullptr;
    const float* Afp = (EPI == 0) ? Af + (size_t)m0 * K : nullptr;

    float4 ar0[4], ar1[4];
    if (EPI == 0) {
#pragma unroll
        for (int i = 0; i < 4; ++i) {
            int row = i * 32 + rsub;
            const float* src = Afp + (size_t)row * K + (tid & 7) * 8;
            ar0[i] = *(const float4*)src;
            ar1[i] = *(const float4*)(src + 4);
        }
    }

    f32x4 acc[4][4] = {};

    for (int k0 = 0; k0 < K; k0 += 64) {
        if (k0) __syncthreads();
#pragma unroll
        for (int i = 0; i < 4; ++i) {
            int row = i * 32 + rsub;
            int cbs = cb0 ^ ((row & SWZ) << 4);
            size_t roff = (size_t)row * ldb + (size_t)(k0 * 2 + cbs);
            gload16(Wb + roff, smem + 8192 + i * 2048 + wofs);
            if (EPI == 1) gload16(Ab + roff, smem + i * 2048 + wofs);
        }
        if (EPI == 0) {     // convert regs -> bf16, write to swizzled LDS col
#pragma unroll
            for (int i = 0; i < 4; ++i) {
                int row = i * 32 + rsub;
                union { ushort us[8]; bf16x8 v; } pk;
                pk.us[0] = f2bu(ar0[i].x); pk.us[1] = f2bu(ar0[i].y);
                pk.us[2] = f2bu(ar0[i].z); pk.us[3] = f2bu(ar0[i].w);
                pk.us[4] = f2bu(ar1[i].x); pk.us[5] = f2bu(ar1[i].y);
                pk.us[6] = f2bu(ar1[i].z); pk.us[7] = f2bu(ar1[i].w);
                int off = row * 64 + ((cb0 ^ ((row & SWZ) << 4)) >> 1);
                *(bf16x8*)&smem[off] = pk.v;
            }
        }
        __syncthreads();
        if (EPI == 0 && k0 + 64 < K) {      // prefetch next BK under MFMA
#pragma unroll
            for (int i = 0; i < 4; ++i) {
                int row = i * 32 + rsub;
                const float* src = Afp + (size_t)row * K + (k0 + 64) + (tid & 7) * 8;
                ar0[i] = *(const float4*)src;
                ar1[i] = *(const float4*)(src + 4);
            }
        }

#pragma unroll
        for (int ks = 0; ks < 2; ++ks) {
            bf16x8 af[4], wf[4];
            const int cb = ((ks * 64 + koffb) ^ swz) >> 1;
#pragma unroll
            for (int f = 0; f < 4; ++f) {
                int rA = wm * 64 + f * 16 + lm;
                int rW = wn * 64 + f * 16 + lm;
                af[f] = *(const bf16x8*)&smem[rA * 64 + cb];
                wf[f] = *(const bf16x8*)&smem[8192 + rW * 64 + cb];
            }
            __builtin_amdgcn_s_setprio(1);
#pragma unroll
            for (int fm = 0; fm < 4; ++fm)
#pragma unroll
                for (int fn = 0; fn < 4; ++fn)
                    acc[fm][fn] = __builtin_amdgcn_mfma_f32_16x16x32_bf16(
                        wf[fn], af[fm], acc[fm][fn], 0, 0, 0);
            __builtin_amdgcn_s_setprio(0);
        }
    }

    // epilogue: lane holds C[m = wm*64+fm*16+lm][n = wn*64+fn*16+(l>>4)*4 + e]
    const int ln4 = (l >> 4) * 4;
    if (EPI == 0) {
        if (n0 < 1024) {       // Q, K panels: coalesced rows of qkv buffer
#pragma unroll
            for (int fm = 0; fm < 4; ++fm) {
                int m = m0 + wm * 64 + fm * 16 + lm;
                ushort* rowp = outb + (size_t)m * ldc + n0 + wn * 64 + ln4;
#pragma unroll
                for (int fn = 0; fn < 4; ++fn) {
                    ushort4 u;
                    u.x = f2bu(acc[fm][fn][0]); u.y = f2bu(acc[fm][fn][1]);
                    u.z = f2bu(acc[fm][fn][2]); u.w = f2bu(acc[fm][fn][3]);
                    *(ushort4*)(rowp + fn * 16) = u;
                }
            }
        } else {               // V panels: transposed scatter into vt[pr][64][784]
            const int hh = ((n0 - 1024) >> 6) + wn;        // wave-uniform head
#pragma unroll
            for (int fm = 0; fm < 4; ++fm) {
                int m = m0 + wm * 64 + fm * 16 + lm;
                int bfi = m / 784;
                int j   = m - bfi * 784;
                ushort* vdst = vtout + ((size_t)(bfi * 8 + hh)) * 50176 + j;
#pragma unroll
                for (int fn = 0; fn < 4; ++fn) {
                    const int dbase = fn * 16 + ln4;
#pragma unroll
                    for (int e = 0; e < 4; ++e)
                        vdst[(size_t)(dbase + e) * 784] = f2bu(acc[fm][fn][e]);
                }
            }
        }
    } else {
#pragma unroll
        for (int fm = 0; fm < 4; ++fm) {
            int m = m0 + wm * 64 + fm * 16 + lm;
            float* rowp = outf + (size_t)m * ldc + n0 + wn * 64 + ln4;
#pragma unroll
            for (int fn = 0; fn < 4; ++fn) {
                float4 b4 = *(const float4*)&bias[n0 + wn * 64 + fn * 16 + ln4];
                float4 o;
                o.x = acc[fm][fn][0] + b4.x; o.y = acc[fm][fn][1] + b4.y;
                o.z = acc[fm][fn][2] + b4.z; o.w = acc[fm][fn][3] + b4.w;
                *(float4*)(rowp + fn * 16) = o;
            }
        }
    }
}

// ---------------------------------------------------------------------------
// MFMA flash attention (32x32x16 bf16), swapped operands — round-8 shape
// (256 thr / 4 waves / 32 q-rows per wave / 2-buffer depth-1 staging /
// one __syncthreads per tile / no-max softmax / in-register P) with ONE
// isolated change vs the confirmed 179.8us baseline: POINTER-INCREMENT
// staging. t<11 needs no clamps (K rows <=767; swizzled V access stays
// in-row for jn<=704), so the per-tile address math (row clamp + mul +
// 64-bit adds, ~35 VALU ops) collapses to 4 pointer increments; the
// clamped path peels to t==11 only. This addressing shipped correct in
// r10/r11 (absmax identical); isolated here without r10's dacc regression.
// ---------------------------------------------------------------------------
__global__ __launch_bounds__(256, 4)
void attn_mfma(const ushort* __restrict__ qkv, const ushort* __restrict__ vt,
               ushort* __restrict__ oh)
{
    __shared__ __align__(16) ushort Ks[2][4096];   // [j 0..63][d 0..63] swizzled
    __shared__ __align__(16) ushort Vs[2][4096];   // [d 0..63][j 0..63] swizzled
    const int tid = threadIdx.x;
    const int l   = tid & 63;
    const int li  = l & 31;
    const int h5  = l >> 5;
    const int w   = tid >> 6;

    const int bid  = blockIdx.x;
    const int xcd  = bid & 7;
    const int slot = bid >> 3;            // 0..223
    const int pr   = (xcd << 5) + slot / 7;
    const int qt   = slot % 7;
    const int hh   = pr & 7;
    const int bfi  = pr >> 3;
    const size_t rowbase = (size_t)bfi * NSP;
    const int iq = qt * 128 + w * 32 + li;
    const bool qvalid = iq < NSP;
    const int iqc = qvalid ? iq : NSP - 1;

    // Q fragments (held all pass): d = ks*16 + h5*8 + 0..7
    bf16x8 qf[4];
    {
        const ushort* qrow = qkv + (rowbase + iqc) * 1536 + hh * 64 + h5 * 8;
#pragma unroll
        for (int ks = 0; ks < 4; ++ks)
            qf[ks] = *(const bf16x8*)(qrow + ks * 16);
    }

    const char* kb0   = (const char*)(qkv + rowbase * 1536 + 512 + hh * 64);
    const char* vbase = (const char*)(vt + (size_t)pr * (64 * NSP));

    const int srow = tid >> 3;           // 0..31
    const int sg16 = (tid & 7) * 16;
    const int sswz = sg16 ^ ((srow & 7) << 4);   // rows srow, srow+32, 64+srow, 96+srow share (row&7)

    float l_run = 0.f;
    f32x16 o0 = {}, o1 = {};

    const int rsw  = (li & 7) << 4;
    const int base0 = li * 128;
    const int base1 = (32 + li) * 128;

    // ---- prologue: stage tile 0 into buf 0 ----
#pragma unroll
    for (int i = 0; i < 2; ++i) {
        int row = i * 32 + srow;
        gload16(kb0 + (size_t)row * 3072 + sswz, &Ks[0][i * 2048 + tid * 8]);
        gload16(vbase + (size_t)row * 1568 + sswz, &Vs[0][i * 2048 + tid * 8]);
    }
    __syncthreads();

    // staging pointers for jn = 64 (first in-loop stage)
    const char* kp0 = kb0 + (size_t)(64 + srow) * 3072 + sswz;
    const char* kp1 = kb0 + (size_t)(96 + srow) * 3072 + sswz;
    const char* vp0 = vbase + (size_t)srow * 1568 + 128 + sswz;
    const char* vp1 = vbase + (size_t)(32 + srow) * 1568 + 128 + sswz;

    int cur = 0;
    for (int t = 0; t < 13; ++t) {
        const int j0 = t * 64;
        // ---- issue next-tile stage into other buffer ----
        if (t < 11) {                 // clean fast path: no clamps needed
            gload16(kp0, &Ks[cur ^ 1][tid * 8]);
            gload16(kp1, &Ks[cur ^ 1][2048 + tid * 8]);
            gload16(vp0, &Vs[cur ^ 1][tid * 8]);
            gload16(vp1, &Vs[cur ^ 1][2048 + tid * 8]);
            kp0 += 196608; kp1 += 196608;   // 64 rows * 3072 B
            vp0 += 128;    vp1 += 128;      // 64 cols * 2 B
        } else if (t == 11) {         // peeled: stage jn=768 with clamps
#pragma unroll
            for (int i = 0; i < 2; ++i) {
                int row = i * 32 + srow;
                int jr = 768 + row; if (jr > NSP - 1) jr = NSP - 1;
                gload16(kb0 + (size_t)jr * 3072 + sswz, &Ks[cur ^ 1][i * 2048 + tid * 8]);
                int cb = 1536 + sswz;
                if (cb + 16 > NSP * 2) cb = 1536;   // stay in valid row data
                gload16(vbase + (size_t)row * 1568 + cb, &Vs[cur ^ 1][i * 2048 + tid * 8]);
            }
        }

        const char* KsC = (const char*)&Ks[cur][0];
        const char* VsC = (const char*)&Vs[cur][0];

        // ---- S^T = mfma(K, Q) ----
        f32x16 s0 = {}, s1 = {};
        __builtin_amdgcn_s_setprio(1);
#pragma unroll
        for (int ks = 0; ks < 4; ++ks) {
            int cb = (ks * 32 + h5 * 16) ^ rsw;
            bf16x8 k0 = *(const bf16x8*)(KsC + base0 + cb);
            bf16x8 k1 = *(const bf16x8*)(KsC + base1 + cb);
            s0 = __builtin_amdgcn_mfma_f32_32x32x16_bf16(k0, qf[ks], s0, 0, 0, 0);
            s1 = __builtin_amdgcn_mfma_f32_32x32x16_bf16(k1, qf[ks], s1, 0, 0, 0);
        }
        __builtin_amdgcn_s_setprio(0);

        if (j0 + 64 > NSP) {   // tail mask -> exp2 gives exact 0
#pragma unroll
            for (int r = 0; r < 16; ++r) {
                int jl = (r & 3) + 8 * (r >> 2) + 4 * h5;
                if (j0 + jl >= NSP)      s0[r] = -1e30f;
                if (j0 + 32 + jl >= NSP) s1[r] = -1e30f;
            }
        }

        // ---- no-max softmax: p = exp2(s), l += sum(p) ----
        float p0[16], p1[16];
        float rs = 0.f;
#pragma unroll
        for (int r = 0; r < 16; ++r) { p0[r] = exp2f(s0[r]); rs += p0[r]; }
#pragma unroll
        for (int r = 0; r < 16; ++r) { p1[r] = exp2f(s1[r]); rs += p1[r]; }
        rs += __shfl_xor(rs, 32);
        l_run += rs;

        // ---- PV: P fragment via cvt_pk + permlane32_swap (no LDS) ----
#pragma unroll
        for (int js = 0; js < 4; ++js) {
            const int rb = (js & 1) * 8;
            float e0 = (js < 2) ? p0[rb + 0] : p1[rb + 0];
            float e1 = (js < 2) ? p0[rb + 1] : p1[rb + 1];
            float e2 = (js < 2) ? p0[rb + 2] : p1[rb + 2];
            float e3 = (js < 2) ? p0[rb + 3] : p1[rb + 3];
            float e4 = (js < 2) ? p0[rb + 4] : p1[rb + 4];
            float e5 = (js < 2) ? p0[rb + 5] : p1[rb + 5];
            float e6 = (js < 2) ? p0[rb + 6] : p1[rb + 6];
            float e7 = (js < 2) ? p0[rb + 7] : p1[rb + 7];
            uint A0, A1, B0, B1;
            asm("v_cvt_pk_bf16_f32 %0, %1, %2" : "=v"(A0) : "v"(e0), "v"(e1));
            asm("v_cvt_pk_bf16_f32 %0, %1, %2" : "=v"(A1) : "v"(e2), "v"(e3));
            asm("v_cvt_pk_bf16_f32 %0, %1, %2" : "=v"(B0) : "v"(e4), "v"(e5));
            asm("v_cvt_pk_bf16_f32 %0, %1, %2" : "=v"(B1) : "v"(e6), "v"(e7));
            asm volatile("v_permlane32_swap_b32 %0, %1" : "+v"(A0), "+v"(B0));
            asm volatile("v_permlane32_swap_b32 %0, %1" : "+v"(A1), "+v"(B1));
            union { uint u[4]; bf16x8 v; } pf;
            pf.u[0] = A0; pf.u[1] = A1; pf.u[2] = B0; pf.u[3] = B1;

            int cb = (js * 32 + h5 * 16) ^ rsw;
            bf16x8 v0f = *(const bf16x8*)(VsC + base0 + cb);
            bf16x8 v1f = *(const bf16x8*)(VsC + base1 + cb);
            __builtin_amdgcn_s_setprio(1);
            o0 = __builtin_amdgcn_mfma_f32_32x32x16_bf16(v0f, pf.v, o0, 0, 0, 0);
            o1 = __builtin_amdgcn_mfma_f32_32x32x16_bf16(v1f, pf.v, o1, 0, 0, 0);
            __builtin_amdgcn_s_setprio(0);
        }

        __syncthreads();   // drains vmcnt (next-tile stage) + buffer swap
        cur ^= 1;
    }

    if (qvalid) {
        float inv = 1.0f / l_run;
        size_t ro = (rowbase + iq) * 512 + hh * 64;
#pragma unroll
        for (int g = 0; g < 4; ++g) {
            int d = g * 8 + h5 * 4;
            ushort4 uh0, uh1;
#pragma unroll
            for (int m = 0; m < 4; ++m) {
                ((ushort*)&uh0)[m] = f2bu(o0[g * 4 + m] * inv);
                ((ushort*)&uh1)[m] = f2bu(o1[g * 4 + m] * inv);
            }
            *(ushort4*)&oh[ro + d]      = uh0;
            *(ushort4*)&oh[ro + 32 + d] = uh1;
        }
    }
}

// ---------------------------------------------------------------------------
extern "C" void kernel_launch(void* const* d_in, const int* in_sizes, int n_in,
                              void* d_out, int out_size, void* d_ws, size_t ws_size,
                              hipStream_t stream) {
    const float* x     = (const float*)d_in[0];   // [2,12544,512]
    const float* Wqkv  = (const float*)d_in[1];   // [1536,512]
    const float* Wproj = (const float*)d_in[2];   // [512,512]
    const float* bproj = (const float*)d_in[3];   // [512]
    float* out = (float*)d_out;

    char* ws = (char*)d_ws;
    ushort* aout  = (ushort*)(ws);                 // 25,690,112 B: attn-out bf16
    ushort* qkvb  = (ushort*)(ws + 25690112);      // 77,070,336 B: q|k|(v unused) bf16
    ushort* wqkvb = (ushort*)(ws + 102760448);     //  1,572,864 B
    ushort* wpb   = (ushort*)(ws + 104333312);     //    524,288 B

    // Vt lives in d_out (51.4 MB fp32 buffer; we need 25.7 MB bf16), written
    // directly by the QKV GEMM's V-panel epilogue (transposed), consumed by
    // attn_mfma, then overwritten by the proj GEMM's final output.
    ushort* vtb = (ushort*)d_out;

    dim3 blk(256);
    cvt_w_kernel<<<1024, blk, 0, stream>>>(Wqkv, Wproj, wqkvb, wpb);

    // QKV: fp32 x (fused bf16 cvt) x Wqkv^T -> Q,K rows in qkvb + Vt in d_out
    gemm_mfma<0><<<dim3(2352), blk, 0, stream>>>(
        x, nullptr, wqkvb, nullptr, qkvb, vtb, nullptr, 512, 1536, 12);

    // spatial attention -> bf16 [25088,512]
    attn_mfma<<<dim3(1792), blk, 0, stream>>>(qkvb, vtb, aout);

    // proj: plain bf16 GEMM + bias -> fp32 out
    gemm_mfma<1><<<dim3(784), blk, 0, stream>>>(
        nullptr, aout, wpb, bproj, nullptr, nullptr, out, 512, 512, 4);
}